// Round 1
// baseline (203.475 us; speedup 1.0000x reference)
//
#include <hip/hip_runtime.h>

// Correlation via banded bf16 MFMA GEMM, v6: A-row register residency.
// out[b, di*21+dj, i, j] = sum_c x1p[b,c,i+di-10,j+dj-10] * x2[b,c,i,j]
//
// Pass 1 (transpose_x1): unchanged — bf16 channel-contiguous x1 copy in d_ws,
//   16B chunks XOR-swizzled (chunk' = cg ^ (col&15)).
// Pass 2 (corr_mfma): KEY CHANGE vs v5: each (i,di) output plane is complete
//   after ONE x1T row's MFMAs (contraction is over c only), so remap
//   wave := x1T row (r ≡ wave mod 4) instead of wave := output row i.
//   A-fragments (16 x short8 = 64 VGPR) are loaded from LDS ONCE per row and
//   consumed over 4 steps for the 4 pairs (i = i0+p, di = r-p), p = 0..3.
//   -> A ds_read_b128 per block: 1344 -> 384 (-71%). B-frags for all 4 i-rows
//   cached in registers (128 VGPR); total ~230 VGPR, capped by
//   __launch_bounds__(256,2). Static per-p branch keeps all array indices
//   compile-time (no scratch).
//   Window: 3 rolling buffers (read buf s%3, stage row s+2 into (s+2)%3;
//   only the p==0 wave reads LDS each step, so 3 buffers suffice).
//   27 steps (ramp w..w+24 staggered), one __syncthreads per step.
//   Epilogue: patch PS 37->36 so va/vb/vc land as aligned ds_write_b128
//   (chunk id (9*n16+q)%8 is a perfect spread -> conflict-free).
//   LDS: 3*13,312 + 4*16*36*4 = 49,152 B; occupancy 2 blocks/CU (VGPR-capped).
// Note: dur_us also contains harness poison fills (~2x67us @86% HBM peak,
//   fillBufferAligned 462MB) that we cannot control; kernel share is ~50us.

#define NB 4
#define NC 128
#define NW 128
#define NH 128
#define DW 21
#define PAD 10
#define NROW_T 148   // NW + 2*PAD
#define NCOL_T 160   // padded cols (148..159 zero)
#define NCH 441
#define PS 36        // patch col stride (col-major [16 cols][36 rows]), 16B-aligned cols
#define SCOLS 52     // slice cols: 32 out + 20 halo
#define SUS (SCOLS * NC)        // 6656 ushorts = 13,312 B
#define ROW_US (NCOL_T * NC)    // 20480 ushorts per full x1T row
#define NBUF 3

typedef __attribute__((ext_vector_type(8))) short short8;   // 8 bf16
typedef __attribute__((ext_vector_type(4))) float float4v;  // 4 fp32

__device__ inline ushort f2bf(float f) {
    union { float f; uint u; } v; v.f = f;
    const uint u = v.u;
    return (ushort)((u + 0x7fffu + ((u >> 16) & 1u)) >> 16);  // RNE
}

__device__ inline void async_copy16(const void* g, void* l) {
    __builtin_amdgcn_global_load_lds(
        (const __attribute__((address_space(1))) void*)g,
        (__attribute__((address_space(3))) void*)l, 16, 0, 0);
}

// Stage one 13,312 B row slice: 3 full 4 KB rounds + 1 KB tail (wave 0 only).
__device__ inline void stage_row(const ushort* src, ushort* dst, int t) {
    const char* s = (const char*)src;
    char* d = (char*)dst;
    #pragma unroll
    for (int it = 0; it < 3; ++it) {
        const int off = it * 4096 + t * 16;
        async_copy16(s + off, d + off);
    }
    if (t < 64) {
        const int off = 12288 + t * 16;
        async_copy16(s + off, d + off);
    }
}

// One block per (b, padded row r). (unchanged from v5)
__global__ __launch_bounds__(256) void transpose_x1(const float* __restrict__ x1,
                                                    ushort* __restrict__ x1T) {
    __shared__ uint tile[128][65];
    const int t = threadIdx.x;
    const int b = blockIdx.x / NROW_T;
    const int r = blockIdx.x % NROW_T;
    const int w = r - PAD;
    const bool inr = (w >= 0 && w < NW);
    if (inr) {
        #pragma unroll
        for (int it = 0; it < 8; ++it) {
            const int u = it * 256 + t;
            const int g4 = u & 31;          // float4 group along h (coalesced)
            const int cp = u >> 5;          // channel pair
            const float4 va = *(const float4*)&x1[(((size_t)b * NC + 2 * cp    ) * NW + w) * NH + g4 * 4];
            const float4 vb = *(const float4*)&x1[(((size_t)b * NC + 2 * cp + 1) * NW + w) * NH + g4 * 4];
            tile[g4 * 4 + 0][cp] = (uint)f2bf(va.x) | ((uint)f2bf(vb.x) << 16);
            tile[g4 * 4 + 1][cp] = (uint)f2bf(va.y) | ((uint)f2bf(vb.y) << 16);
            tile[g4 * 4 + 2][cp] = (uint)f2bf(va.z) | ((uint)f2bf(vb.z) << 16);
            tile[g4 * 4 + 3][cp] = (uint)f2bf(va.w) | ((uint)f2bf(vb.w) << 16);
        }
    }
    __syncthreads();
    #pragma unroll
    for (int it = 0; it < 10; ++it) {
        const int u = it * 256 + t;
        const int cg = u & 15;
        const int col = u >> 4;             // 0..159
        uint4 v = make_uint4(0, 0, 0, 0);
        const int h = col - PAD;
        if (inr && h >= 0 && h < NH) {
            v.x = tile[h][cg * 4 + 0];
            v.y = tile[h][cg * 4 + 1];
            v.z = tile[h][cg * 4 + 2];
            v.w = tile[h][cg * 4 + 3];
        }
        const int chunk = cg ^ (col & 15);  // swizzle for conflict-free pass-2 reads
        *(uint4*)&x1T[(((size_t)b * NROW_T + r) * NCOL_T + col) * NC + chunk * 8] = v;
    }
}

// One (i, di) pair: 24 MFMA + band-extract epilogue. All indices static
// (called with literal pair index so Bfp/Af never dynamically indexed).
__device__ __forceinline__ void do_pair(const short8 (&Af)[4][4],
                                        const short8 (&Bfp)[2][4],
                                        float* P, float* __restrict__ out,
                                        int b, int di, int i, int col0,
                                        int n16, int q, int lane) {
    float4v a00 = {0.f,0.f,0.f,0.f}, a01 = {0.f,0.f,0.f,0.f}, a02 = {0.f,0.f,0.f,0.f};
    float4v a10 = {0.f,0.f,0.f,0.f}, a11 = {0.f,0.f,0.f,0.f}, a12 = {0.f,0.f,0.f,0.f};
    #pragma unroll
    for (int k4 = 0; k4 < 4; ++k4) {
        a00 = __builtin_amdgcn_mfma_f32_16x16x32_bf16(Af[0][k4], Bfp[0][k4], a00, 0, 0, 0);
        a01 = __builtin_amdgcn_mfma_f32_16x16x32_bf16(Af[1][k4], Bfp[0][k4], a01, 0, 0, 0);
        a02 = __builtin_amdgcn_mfma_f32_16x16x32_bf16(Af[2][k4], Bfp[0][k4], a02, 0, 0, 0);
        a10 = __builtin_amdgcn_mfma_f32_16x16x32_bf16(Af[1][k4], Bfp[1][k4], a10, 0, 0, 0);
        a11 = __builtin_amdgcn_mfma_f32_16x16x32_bf16(Af[2][k4], Bfp[1][k4], a11, 0, 0, 0);
        a12 = __builtin_amdgcn_mfma_f32_16x16x32_bf16(Af[3][k4], Bfp[1][k4], a12, 0, 0, 0);
    }
    // Band-extract via per-wave col-major patch P[n*PS + m_rel], PS=36 so the
    // three writes are aligned ds_write_b128 (conflict-free chunk spread).
    #pragma unroll
    for (int nt = 0; nt < 2; ++nt) {
        const float4v va = nt ? a10 : a00;   // rel rows 0..15
        const float4v vb = nt ? a11 : a01;   // rel rows 16..31
        const float4v vc = nt ? a12 : a02;   // nt0 q==0 / nt1 q==3 -> rows 32..35
        *(float4v*)&P[n16 * PS + q * 4]      = va;
        *(float4v*)&P[n16 * PS + 16 + q * 4] = vb;
        if (q == (nt ? 3 : 0))
            *(float4v*)&P[n16 * PS + 32] = vc;
        #pragma unroll
        for (int it2 = 0; it2 < 2; ++it2) {
            const int u = it2 * 64 + lane;
            if (u < 84) {
                const int dj = u >> 2;
                const int jj = (u & 3) * 4;
                float4v v;
                #pragma unroll
                for (int pp = 0; pp < 4; ++pp)
                    v[pp] = P[(jj + pp) * (PS + 1) + dj];  // col jj+pp, row jj+pp+dj
                *(float4v*)&out[(((size_t)(b * NCH + di * DW + dj)) * NW + i) * NH
                                + col0 + nt * 16 + jj] = v;
            }
        }
    }
}

// Block = (b, i-quad, j-quarter), XCD-swizzled. 256 threads = 4 waves.
// Wave w owns x1T rows r = w, w+4, ..., w+20 (local); at global step s the
// wave is at pair p = (s-w)&3 of row r = s-p. p==0 loads A-frags from LDS;
// p=0..3 consume them against Bf[p] (i = i0+p, di = r-p). 21 pairs/wave.
__global__ __launch_bounds__(256, 2) void corr_mfma(const ushort* __restrict__ x1T,
                                                    const float* __restrict__ x2,
                                                    float* __restrict__ out) {
    __shared__ ushort win[NBUF][SUS];        // 39,936 B rolling row window
    __shared__ float patch[4][16 * PS];      // 9,216 B

    const int t = threadIdx.x;
    const int wave = t >> 6;
    const int lane = t & 63;
    const int n16 = lane & 15;
    const int q = lane >> 4;

    // XCD swizzle: hw XCD = blockIdx%8 -> XCD k serves (b = k>>1, ihalf = k&1),
    // 64 slots = 16 i-quads x 4 j-quarters (x1T band ~3.4 MB, fits 4 MB L2).
    const int n = blockIdx.x;
    const int b = (n & 7) >> 1;
    const int ihalf = n & 1;
    const int slot = n >> 3;                 // 0..63
    const int iq = ihalf * 16 + (slot >> 2);
    const int jq = slot & 3;
    const int i0 = iq * 4;
    const int col0 = jq * 32;

    const ushort* xbase = x1T + (size_t)(b * NROW_T) * ROW_US + (size_t)col0 * NC;

    // prologue: stage rows 0,1 into buffers 0,1 (buffer = row % 3)
    stage_row(xbase + (size_t)i0 * ROW_US, win[0], t);
    stage_row(xbase + (size_t)(i0 + 1) * ROW_US, win[1], t);

    // B fragments from fp32 x2 for ALL 4 output rows i0..i0+3 (128 VGPR).
    // Identical across the 4 waves -> L1/L2 serve the repeats; one-time cost.
    short8 Bf[4][2][4];
    #pragma unroll
    for (int ii = 0; ii < 4; ++ii) {
        #pragma unroll
        for (int nt = 0; nt < 2; ++nt) {
            const int jc = col0 + nt * 16 + n16;
            #pragma unroll
            for (int k4 = 0; k4 < 4; ++k4) {
                short8 sv;
                #pragma unroll
                for (int e = 0; e < 8; ++e) {
                    const int c = k4 * 32 + q * 8 + e;
                    sv[e] = (short)f2bf(x2[(((size_t)b * NC + c) * NW + (i0 + ii)) * NH + jc]);
                }
                Bf[ii][nt][k4] = sv;
            }
        }
    }

    __syncthreads();  // prologue staging + B loads drained

    short8 Af[4][4];                         // current row's A-frags (64 VGPR)
    float* P = &patch[wave][0];

    for (int s = 0; s < 27; ++s) {
        // stage row s+2 into buffer (s+2)%3 (all threads; async, drained at barrier)
        if (s + 2 <= 23)
            stage_row(xbase + (size_t)(i0 + s + 2) * ROW_US, win[(s + 2) % NBUF], t);

        const int d = s - wave;
        const int p = d & 3;
        const int r = s - p;                 // wave's current row (valid when d>=0)

        if (d >= 0 && r <= 23) {
            if (p == 0) {
                // load A-frags for row r from win[r%3] (only LDS reader this step)
                const ushort* A = win[r % NBUF];
                #pragma unroll
                for (int k4 = 0; k4 < 4; ++k4) {
                    const int kc = q + 4 * k4;
                    #pragma unroll
                    for (int tl = 0; tl < 4; ++tl) {
                        const int base = (tl < 3) ? tl * 16 : 36;
                        const int c = base + n16;
                        Af[tl][k4] = *(const short8*)&A[c * NC + ((kc ^ (c & 15)) & 15) * 8];
                    }
                }
                if (r <= 20)
                    do_pair(Af, Bf[0], P, out, b, r,     i0,     col0, n16, q, lane);
            } else if (p == 1) {
                if (r >= 1 && r <= 21)
                    do_pair(Af, Bf[1], P, out, b, r - 1, i0 + 1, col0, n16, q, lane);
            } else if (p == 2) {
                if (r >= 2 && r <= 22)
                    do_pair(Af, Bf[2], P, out, b, r - 2, i0 + 2, col0, n16, q, lane);
            } else {
                if (r >= 3)
                    do_pair(Af, Bf[3], P, out, b, r - 3, i0 + 3, col0, n16, q, lane);
            }
        }
        __syncthreads();  // window rotation: staged buffer ready / read buffer free
    }
}

extern "C" void kernel_launch(void* const* d_in, const int* in_sizes, int n_in,
                              void* d_out, int out_size, void* d_ws, size_t ws_size,
                              hipStream_t stream) {
    const float* x1 = (const float*)d_in[0];
    const float* x2 = (const float*)d_in[1];
    float* out = (float*)d_out;
    ushort* x1T = (ushort*)d_ws;  // 4*148*160*128*2 = 24,248,320 B
    transpose_x1<<<dim3(NB * NROW_T), dim3(256), 0, stream>>>(x1, x1T);
    corr_mfma<<<dim3(NB * 32 * 4), dim3(256), 0, stream>>>(x1T, x2, out);
}

// Round 2
// 187.616 us; speedup vs baseline: 1.0845x; 1.0845x over previous
//
#include <hip/hip_runtime.h>

// Correlation via banded bf16 MFMA GEMM, v7 = v5 + counted-vmcnt step barrier.
// out[b, di*21+dj, i, j] = sum_c x1p[b,c,i+di-10,j+dj-10] * x2[b,c,i,j]
//
// Pass 1 (transpose_x1): bf16 channel-contiguous x1 copy in d_ws:
//   x1T[b][r 0..147][col 0..159][c], 16B chunks XOR-swizzled chunk' = cg ^ (col&15).
// Pass 2 (corr_mfma): block = (b, i-quad, j-quarter), 4 waves = 4 output rows,
//   XCD-swizzled grid (XCD k = one (b, i-half) band; x1T slice set 3.4 MB < 4 MB L2).
//   5-buffer rolling window of 52-col row slices; ONE barrier per di-iteration.
//   v7 CHANGE (only change vs v5): the step barrier no longer drains output
//   stores. Issue order is pinned [A ds_reads][stage][sched_barrier(0)][MFMA]
//   [epilogue: 4 stores], and the step ends with
//       s_waitcnt vmcnt(4); s_barrier
//   Per wave, the newest 4 VMEM ops are exactly this step's 4 output stores
//   (2 nt x 2 it2, all issued: it2=1 has lanes 0..19 active). vmcnt(4) thus
//   drains this step's staging global_load_lds (older) and last step's stores,
//   while this step's stores retire in the background during the next step.
//   __syncthreads()'s vmcnt(0) was serializing ~21.5 KB/step/CU of HBM writes
//   into the critical path.
//   LDS: 5*13,312 + 4*2,368 = 76,032 B -> 2 blocks/CU (8 waves/CU).
// v6 lessons kept out: no 4-row B register cache (spilled at VGPR_Count=128,
//   +30 MB scratch traffic), patch stays PS=37 scalar (measured 0 bank
//   conflicts; PS=36 b128 writes were 8-way conflicted, 1.03M cycles).

#define NB 4
#define NC 128
#define NW 128
#define NH 128
#define DW 21
#define PAD 10
#define NROW_T 148   // NW + 2*PAD
#define NCOL_T 160   // padded cols (148..159 zero)
#define NCH 441
#define PS 37        // patch col stride (col-major [16 cols][37 rows])
#define SCOLS 52     // slice cols: 32 out + 20 halo
#define SUS (SCOLS * NC)        // 6656 ushorts = 13,312 B
#define ROW_US (NCOL_T * NC)    // 20480 ushorts per full x1T row

typedef __attribute__((ext_vector_type(8))) short short8;   // 8 bf16
typedef __attribute__((ext_vector_type(4))) float float4v;  // 4 fp32

__device__ inline ushort f2bf(float f) {
    union { float f; uint u; } v; v.f = f;
    const uint u = v.u;
    return (ushort)((u + 0x7fffu + ((u >> 16) & 1u)) >> 16);  // RNE
}

__device__ inline void async_copy16(const void* g, void* l) {
    __builtin_amdgcn_global_load_lds(
        (const __attribute__((address_space(1))) void*)g,
        (__attribute__((address_space(3))) void*)l, 16, 0, 0);
}

// Stage one 13,312 B row slice: 3 full 4 KB rounds + 1 KB tail (wave 0 only).
// Wave 0 issues 4 global_load_lds, waves 1-3 issue 3 (all OLDER than the
// epilogue's 4 stores -> covered by the step-end vmcnt(4)).
__device__ inline void stage_row(const ushort* src, ushort* dst, int t) {
    const char* s = (const char*)src;
    char* d = (char*)dst;
    #pragma unroll
    for (int it = 0; it < 3; ++it) {
        const int off = it * 4096 + t * 16;
        async_copy16(s + off, d + off);
    }
    if (t < 64) {
        const int off = 12288 + t * 16;
        async_copy16(s + off, d + off);
    }
}

// One block per (b, padded row r).
__global__ __launch_bounds__(256) void transpose_x1(const float* __restrict__ x1,
                                                    ushort* __restrict__ x1T) {
    __shared__ uint tile[128][65];
    const int t = threadIdx.x;
    const int b = blockIdx.x / NROW_T;
    const int r = blockIdx.x % NROW_T;
    const int w = r - PAD;
    const bool inr = (w >= 0 && w < NW);
    if (inr) {
        #pragma unroll
        for (int it = 0; it < 8; ++it) {
            const int u = it * 256 + t;
            const int g4 = u & 31;          // float4 group along h (coalesced)
            const int cp = u >> 5;          // channel pair
            const float4 va = *(const float4*)&x1[(((size_t)b * NC + 2 * cp    ) * NW + w) * NH + g4 * 4];
            const float4 vb = *(const float4*)&x1[(((size_t)b * NC + 2 * cp + 1) * NW + w) * NH + g4 * 4];
            tile[g4 * 4 + 0][cp] = (uint)f2bf(va.x) | ((uint)f2bf(vb.x) << 16);
            tile[g4 * 4 + 1][cp] = (uint)f2bf(va.y) | ((uint)f2bf(vb.y) << 16);
            tile[g4 * 4 + 2][cp] = (uint)f2bf(va.z) | ((uint)f2bf(vb.z) << 16);
            tile[g4 * 4 + 3][cp] = (uint)f2bf(va.w) | ((uint)f2bf(vb.w) << 16);
        }
    }
    __syncthreads();
    #pragma unroll
    for (int it = 0; it < 10; ++it) {
        const int u = it * 256 + t;
        const int cg = u & 15;
        const int col = u >> 4;             // 0..159
        uint4 v = make_uint4(0, 0, 0, 0);
        const int h = col - PAD;
        if (inr && h >= 0 && h < NH) {
            v.x = tile[h][cg * 4 + 0];
            v.y = tile[h][cg * 4 + 1];
            v.z = tile[h][cg * 4 + 2];
            v.w = tile[h][cg * 4 + 3];
        }
        const int chunk = cg ^ (col & 15);  // swizzle for conflict-free pass-2 reads
        *(uint4*)&x1T[(((size_t)b * NROW_T + r) * NCOL_T + col) * NC + chunk * 8] = v;
    }
}

// Block = (b, i-quad, j-quarter), XCD-swizzled. 256 threads = 4 waves = 4 rows.
__global__ __launch_bounds__(256) void corr_mfma(const ushort* __restrict__ x1T,
                                                 const float* __restrict__ x2,
                                                 float* __restrict__ out) {
    __shared__ ushort win[5][SUS];          // 66,560 B rolling row window
    __shared__ float patch[4][16 * PS];     // 9,472 B

    const int t = threadIdx.x;
    const int wave = t >> 6;                // = row offset 0..3
    const int lane = t & 63;
    const int n16 = lane & 15;
    const int q = lane >> 4;

    // XCD swizzle: hw XCD = blockIdx%8 -> XCD k serves (b = k>>1, ihalf = k&1),
    // 64 slots = 16 i-quads x 4 j-quarters (x1T band ~3.4 MB, fits 4 MB L2).
    const int n = blockIdx.x;
    const int b = (n & 7) >> 1;
    const int ihalf = n & 1;
    const int slot = n >> 3;                // 0..63
    const int iq = ihalf * 16 + (slot >> 2);
    const int jq = slot & 3;
    const int i0 = iq * 4;
    const int col0 = jq * 32;
    const int i = i0 + wave;

    const ushort* xbase = x1T + (size_t)(b * NROW_T) * ROW_US + (size_t)col0 * NC;

    // preload rows i0..i0+3 into buffers 0..3 (buffer = (row - i0) % 5)
    #pragma unroll
    for (int r = 0; r < 4; ++r)
        stage_row(xbase + (size_t)(i0 + r) * ROW_US, win[r], t);

    // B fragments from fp32 x2 (read once per block; lane n=n16, k=q*8+e+32*k4)
    short8 Bf[2][4];
    #pragma unroll
    for (int nt = 0; nt < 2; ++nt) {
        const int jc = col0 + nt * 16 + n16;
        #pragma unroll
        for (int k4 = 0; k4 < 4; ++k4) {
            short8 s;
            #pragma unroll
            for (int e = 0; e < 8; ++e) {
                const int c = k4 * 32 + q * 8 + e;
                s[e] = (short)f2bf(x2[(((size_t)b * NC + c) * NW + i) * NH + jc]);
            }
            Bf[nt][k4] = s;
        }
    }

    __syncthreads();  // preload + B loads drained once (full vmcnt(0) OK here)

    float* P = &patch[wave][0];

    for (int di = 0; di < DW; ++di) {
        const ushort* A = win[(di + wave) % 5];  // wave's A-row = i0 + wave + di

        // 16 ds_read_b128 first (tile bases {0,16,32,36})
        short8 Af[4][4];
        #pragma unroll
        for (int k4 = 0; k4 < 4; ++k4) {
            const int kc = q + 4 * k4;
            #pragma unroll
            for (int tl = 0; tl < 4; ++tl) {
                const int base = (tl < 3) ? tl * 16 : 36;
                const int c = base + n16;
                Af[tl][k4] = *(const short8*)&A[c * NC + ((kc ^ (c & 15)) & 15) * 8];
            }
        }

        // prefetch row i0+di+4 into buffer (di+4)%5; drained at step-end vmcnt(4).
        if (di < DW - 1)
            stage_row(xbase + (size_t)(i0 + di + 4) * ROW_US, win[(di + 4) % 5], t);

        // Pin order: staging loads issued BEFORE the epilogue's stores, so the
        // step-end vmcnt(4) (4 = store count) is guaranteed to cover staging.
        __builtin_amdgcn_sched_barrier(0);

        float4v a00 = {0.f,0.f,0.f,0.f}, a01 = {0.f,0.f,0.f,0.f}, a02 = {0.f,0.f,0.f,0.f};
        float4v a10 = {0.f,0.f,0.f,0.f}, a11 = {0.f,0.f,0.f,0.f}, a12 = {0.f,0.f,0.f,0.f};
        #pragma unroll
        for (int k4 = 0; k4 < 4; ++k4) {
            a00 = __builtin_amdgcn_mfma_f32_16x16x32_bf16(Af[0][k4], Bf[0][k4], a00, 0, 0, 0);
            a01 = __builtin_amdgcn_mfma_f32_16x16x32_bf16(Af[1][k4], Bf[0][k4], a01, 0, 0, 0);
            a02 = __builtin_amdgcn_mfma_f32_16x16x32_bf16(Af[2][k4], Bf[0][k4], a02, 0, 0, 0);
            a10 = __builtin_amdgcn_mfma_f32_16x16x32_bf16(Af[1][k4], Bf[1][k4], a10, 0, 0, 0);
            a11 = __builtin_amdgcn_mfma_f32_16x16x32_bf16(Af[2][k4], Bf[1][k4], a11, 0, 0, 0);
            a12 = __builtin_amdgcn_mfma_f32_16x16x32_bf16(Af[3][k4], Bf[1][k4], a12, 0, 0, 0);
        }

        // Epilogue: per nt, band-extract via per-wave col-major patch P[n*37 + r].
        // Exactly 4 global stores per thread per step (2 nt x 2 it2; it2=1 has
        // lanes 0..19 active so the instruction always issues wave-wide).
        #pragma unroll
        for (int nt = 0; nt < 2; ++nt) {
            const float4v va = nt ? a10 : a00;  // rel rows 0..15
            const float4v vb = nt ? a11 : a01;  // rel rows 16..31
            const float4v vc = nt ? a12 : a02;  // nt0 q==0 / nt1 q==3 -> rows 32..35
            #pragma unroll
            for (int reg = 0; reg < 4; ++reg) {
                P[n16 * PS + q * 4 + reg]      = va[reg];
                P[n16 * PS + 16 + q * 4 + reg] = vb[reg];
            }
            if (q == (nt ? 3 : 0)) {
                #pragma unroll
                for (int reg = 0; reg < 4; ++reg)
                    P[n16 * PS + 32 + reg] = vc[reg];
            }
            #pragma unroll
            for (int it2 = 0; it2 < 2; ++it2) {
                const int u = it2 * 64 + lane;
                if (u < 84) {
                    const int dj = u >> 2;
                    const int jj = (u & 3) * 4;
                    float4v v;
                    #pragma unroll
                    for (int p = 0; p < 4; ++p)
                        v[p] = P[(jj + p) * (PS + 1) + dj];  // col jj+p, row jj+p+dj
                    *(float4v*)&out[(((size_t)(b * NCH + di * DW + dj)) * NW + i) * NH
                                    + col0 + nt * 16 + jj] = v;
                }
            }
        }

        // Step barrier WITHOUT draining this step's output stores:
        // newest 4 VMEM ops per wave = the 4 stores above; everything older
        // (staging global_load_lds, previous step's stores) is drained.
        asm volatile("s_waitcnt vmcnt(4)" ::: "memory");
        __builtin_amdgcn_s_barrier();
        __builtin_amdgcn_sched_barrier(0);
    }
}

extern "C" void kernel_launch(void* const* d_in, const int* in_sizes, int n_in,
                              void* d_out, int out_size, void* d_ws, size_t ws_size,
                              hipStream_t stream) {
    const float* x1 = (const float*)d_in[0];
    const float* x2 = (const float*)d_in[1];
    float* out = (float*)d_out;
    ushort* x1T = (ushort*)d_ws;  // 4*148*160*128*2 = 24,248,320 B
    transpose_x1<<<dim3(NB * NROW_T), dim3(256), 0, stream>>>(x1, x1T);
    corr_mfma<<<dim3(NB * 32 * 4), dim3(256), 0, stream>>>(x1T, x2, out);
}